// Round 5
// baseline (954.703 us; speedup 1.0000x reference)
//
#include <hip/hip_runtime.h>
#include <math.h>

#define B_ 4
#define N_ 5000
#define K_ 16
#define L_ 3
#define F_ 2
#define E_ 32
#define D_ 64
#define H_ 4
#define BN_ (B_*N_)          /* 20000 */
#define NK_ (N_*K_)          /* 80000 */
#define BIG_ 1.0e9f

// ---------------- zero the accumulators -------------------------------------
__global__ void k_zero(float* __restrict__ acc) {
    if (threadIdx.x < 192) acc[threadIdx.x] = 0.f;
}

// ---------------- encoder: h = [emb_norm, feat] @ enc_W + enc_b -------------
__global__ __launch_bounds__(256) void k_encode(
    const float* __restrict__ embed, const float* __restrict__ feat,
    const float* __restrict__ encW, const float* __restrict__ encb,
    float* __restrict__ h)
{
    int wave = threadIdx.x >> 6;
    int lane = threadIdx.x & 63;
    int node = blockIdx.x * 4 + wave;      // b*N+n  in [0,20000)
    int n = node % N_;

    float e = (lane < E_) ? embed[(size_t)n * E_ + lane] : 0.f;
    float ss = e * e;
    #pragma unroll
    for (int m = 32; m >= 1; m >>= 1) ss += __shfl_xor(ss, m, 64);
    float scale = 1.f / fmaxf(sqrtf(ss), 1.f);

    float inval = (lane < E_) ? e * scale
                : (lane < E_ + F_) ? feat[(size_t)node * F_ + (lane - E_)]
                : 0.f;

    float acc = encb[lane];
    #pragma unroll
    for (int i = 0; i < E_ + F_; ++i)
        acc = fmaf(__shfl(inval, i, 64), encW[i * D_ + lane], acc);
    h[(size_t)node * D_ + lane] = acc;
}

// ======================= register-tile GEMM helpers ==========================
// thread layout: cg = tx&15 (c0=cg*4), rg = tx>>4 (r0=rg*4); 64x64 tile/block.
// A from LDS (rows broadcast across the 16 col-threads), W from global (L1).

__device__ __forceinline__ void mm_lds(
    const float* A, const float* __restrict__ W, int r0, int c0, float acc[4][4])
{
    #pragma unroll 2
    for (int i = 0; i < 64; i += 4) {
        float a[4][4];
        #pragma unroll
        for (int k = 0; k < 4; ++k) {
            float4 t = *(const float4*)&A[(r0 + k) * 64 + i];
            a[k][0] = t.x; a[k][1] = t.y; a[k][2] = t.z; a[k][3] = t.w;
        }
        #pragma unroll
        for (int ii = 0; ii < 4; ++ii) {
            float4 w = *(const float4*)&W[(i + ii) * 64 + c0];
            #pragma unroll
            for (int k = 0; k < 4; ++k) {
                acc[k][0] = fmaf(a[k][ii], w.x, acc[k][0]);
                acc[k][1] = fmaf(a[k][ii], w.y, acc[k][1]);
                acc[k][2] = fmaf(a[k][ii], w.z, acc[k][2]);
                acc[k][3] = fmaf(a[k][ii], w.w, acc[k][3]);
            }
        }
    }
}

// dual-W: ak += A@Wk, av += A@Wv
__device__ __forceinline__ void mm_kv(
    const float* A, const float* __restrict__ Wk, const float* __restrict__ Wv,
    int r0, int c0, float ak[4][4], float av[4][4])
{
    #pragma unroll 2
    for (int i = 0; i < 64; i += 4) {
        float a[4][4];
        #pragma unroll
        for (int k = 0; k < 4; ++k) {
            float4 t = *(const float4*)&A[(r0 + k) * 64 + i];
            a[k][0] = t.x; a[k][1] = t.y; a[k][2] = t.z; a[k][3] = t.w;
        }
        #pragma unroll
        for (int ii = 0; ii < 4; ++ii) {
            float4 wk = *(const float4*)&Wk[(i + ii) * 64 + c0];
            float4 wv = *(const float4*)&Wv[(i + ii) * 64 + c0];
            #pragma unroll
            for (int k = 0; k < 4; ++k) {
                float aa = a[k][ii];
                ak[k][0] = fmaf(aa, wk.x, ak[k][0]);
                ak[k][1] = fmaf(aa, wk.y, ak[k][1]);
                ak[k][2] = fmaf(aa, wk.z, ak[k][2]);
                ak[k][3] = fmaf(aa, wk.w, ak[k][3]);
                av[k][0] = fmaf(aa, wv.x, av[k][0]);
                av[k][1] = fmaf(aa, wv.y, av[k][1]);
                av[k][2] = fmaf(aa, wv.z, av[k][2]);
                av[k][3] = fmaf(aa, wv.w, av[k][3]);
            }
        }
    }
}

// guarded global-A: acc += A[rows base..][.] @ W, rows masked by ok[]
__device__ __forceinline__ void mm_glb(
    const float* __restrict__ A, const float* __restrict__ W,
    int r0, int c0, const bool ok[4], float acc[4][4])
{
    #pragma unroll 2
    for (int i = 0; i < 64; i += 4) {
        float a[4][4];
        #pragma unroll
        for (int k = 0; k < 4; ++k) {
            float4 t = ok[k] ? *(const float4*)&A[(size_t)(r0 + k) * 64 + i]
                             : make_float4(0.f, 0.f, 0.f, 0.f);
            a[k][0] = t.x; a[k][1] = t.y; a[k][2] = t.z; a[k][3] = t.w;
        }
        #pragma unroll
        for (int ii = 0; ii < 4; ++ii) {
            float4 w = *(const float4*)&W[(i + ii) * 64 + c0];
            #pragma unroll
            for (int k = 0; k < 4; ++k) {
                acc[k][0] = fmaf(a[k][ii], w.x, acc[k][0]);
                acc[k][1] = fmaf(a[k][ii], w.y, acc[k][1]);
                acc[k][2] = fmaf(a[k][ii], w.z, acc[k][2]);
                acc[k][3] = fmaf(a[k][ii], w.w, acc[k][3]);
            }
        }
    }
}

// dual-A: acc += A1@W1 + A2@W2 (both A from LDS)
__device__ __forceinline__ void mm_2a(
    const float* A1, const float* A2,
    const float* __restrict__ W1, const float* __restrict__ W2,
    int r0, int c0, float acc[4][4])
{
    #pragma unroll 2
    for (int i = 0; i < 64; i += 4) {
        float a1[4][4], a2[4][4];
        #pragma unroll
        for (int k = 0; k < 4; ++k) {
            float4 t = *(const float4*)&A1[(r0 + k) * 64 + i];
            a1[k][0] = t.x; a1[k][1] = t.y; a1[k][2] = t.z; a1[k][3] = t.w;
            float4 u = *(const float4*)&A2[(r0 + k) * 64 + i];
            a2[k][0] = u.x; a2[k][1] = u.y; a2[k][2] = u.z; a2[k][3] = u.w;
        }
        #pragma unroll
        for (int ii = 0; ii < 4; ++ii) {
            float4 w1 = *(const float4*)&W1[(i + ii) * 64 + c0];
            float4 w2 = *(const float4*)&W2[(i + ii) * 64 + c0];
            #pragma unroll
            for (int k = 0; k < 4; ++k) {
                float x1 = a1[k][ii], x2 = a2[k][ii];
                acc[k][0] = fmaf(x1, w1.x, fmaf(x2, w2.x, acc[k][0]));
                acc[k][1] = fmaf(x1, w1.y, fmaf(x2, w2.y, acc[k][1]));
                acc[k][2] = fmaf(x1, w1.z, fmaf(x2, w2.z, acc[k][2]));
                acc[k][3] = fmaf(x1, w1.w, fmaf(x2, w2.w, acc[k][3]));
            }
        }
    }
}

// ================= fused graph layer, part A =================================
// per 64-node block: gather-mean -> states=tanh(@nbW) -> kk,vv -> attn -> x
__global__ __launch_bounds__(256, 2) void k_layerA(
    const float* __restrict__ h, const int* __restrict__ neigh,
    const int* __restrict__ numn,
    const float* __restrict__ nbW, const float* __restrict__ Wq,
    const float* __restrict__ Wk, const float* __restrict__ Wv,
    const float* __restrict__ Wo, float* __restrict__ x)
{
    __shared__ float sT[64 * 64];      // mean -> states -> ao (16KB)
    int tx = threadIdx.x;
    int base = blockIdx.x * 64;
    int cg = tx & 15, rg = tx >> 4;
    int c0 = cg * 4, r0 = rg * 4;
    int wv = tx >> 6, lane = tx & 63;

    bool okr[4];
    #pragma unroll
    for (int k = 0; k < 4; ++k) okr[k] = (base + r0 + k) < BN_;

    // q = h_tile @ Wq  (A straight from global; tile is L1-hot)
    float qv[4][4] = {};
    mm_glb(h + (size_t)base * 64, Wq, r0, c0, okr, qv);

    float av[3][4][4];   // vv kept in registers (t statically unrolled)
    float p[3][4];

    #pragma unroll
    for (int t = 0; t < 3; ++t) {
        __syncthreads();               // prior sT consumers done
        // ---- gather mean_t into sT: wave handles 16 nodes, lane = col ----
        #pragma unroll 1
        for (int i2 = 0; i2 < 16; ++i2) {
            int r = wv * 16 + i2;
            int g = base + r;
            float m = 0.f;
            if (g < BN_) {
                int b = g / N_;
                int pad = numn[b];
                const int* nb = neigh + ((size_t)t * BN_ + g) * K_;
                const float* hb = h + (size_t)b * N_ * D_;
                float sum = 0.f; int cnt = 0;
                #pragma unroll
                for (int k = 0; k < K_; ++k) {
                    int idx = nb[k];
                    if (idx != pad) { sum += hb[(size_t)idx * D_ + lane]; cnt++; }
                }
                m = sum / fmaxf((float)cnt, 1.f);
            }
            sT[r * 64 + lane] = m;
        }
        __syncthreads();
        // ---- states = tanh(mean @ nbW) ----
        float sr[4][4] = {};
        mm_lds(sT, nbW, r0, c0, sr);
        __syncthreads();               // all reads of mean done
        #pragma unroll
        for (int k = 0; k < 4; ++k) {
            float4 o = make_float4(tanhf(sr[k][0]), tanhf(sr[k][1]),
                                   tanhf(sr[k][2]), tanhf(sr[k][3]));
            *(float4*)&sT[(r0 + k) * 64 + c0] = o;
        }
        __syncthreads();
        // ---- kk, vv; score partial ----
        float ak[4][4] = {};
        #pragma unroll
        for (int k = 0; k < 4; ++k)
            #pragma unroll
            for (int j = 0; j < 4; ++j) av[t][k][j] = 0.f;
        mm_kv(sT, Wk, Wv, r0, c0, ak, av[t]);
        #pragma unroll
        for (int k = 0; k < 4; ++k) {
            float pp = ak[k][0] * qv[k][0] + ak[k][1] * qv[k][1]
                     + ak[k][2] * qv[k][2] + ak[k][3] * qv[k][3];
            pp += __shfl_xor(pp, 1, 64);   // 4 col-threads of one head
            pp += __shfl_xor(pp, 2, 64);
            p[t][k] = pp * 0.25f;          // / sqrt(dh=16)
        }
    }

    // ---- softmax over t, ao = sum w_t * vv_t ----
    float ao[4][4];
    #pragma unroll
    for (int k = 0; k < 4; ++k) {
        float p0 = p[0][k], p1 = p[1][k], p2 = p[2][k];
        float mx = fmaxf(p0, fmaxf(p1, p2));
        float e0 = expf(p0 - mx), e1 = expf(p1 - mx), e2 = expf(p2 - mx);
        float inv = 1.f / (e0 + e1 + e2);
        float w0 = e0 * inv, w1 = e1 * inv, w2 = e2 * inv;
        #pragma unroll
        for (int j = 0; j < 4; ++j)
            ao[k][j] = w0 * av[0][k][j] + w1 * av[1][k][j] + w2 * av[2][k][j];
    }
    __syncthreads();                   // last mm_kv reads of sT done
    #pragma unroll
    for (int k = 0; k < 4; ++k)
        *(float4*)&sT[(r0 + k) * 64 + c0] =
            make_float4(ao[k][0], ao[k][1], ao[k][2], ao[k][3]);
    __syncthreads();

    // ---- x = tanh(ao @ Wo) ----
    float xr[4][4] = {};
    mm_lds(sT, Wo, r0, c0, xr);
    #pragma unroll
    for (int k = 0; k < 4; ++k) {
        if (!okr[k]) continue;
        *(float4*)&x[(size_t)(base + r0 + k) * 64 + c0] =
            make_float4(tanhf(xr[k][0]), tanhf(xr[k][1]),
                        tanhf(xr[k][2]), tanhf(xr[k][3]));
    }
}

// ================= fused graph layer, part B (GRU) ===========================
__global__ __launch_bounds__(256, 2) void k_layerB(
    const float* __restrict__ x, float* __restrict__ h,
    const float* __restrict__ Wz, const float* __restrict__ Uz, const float* __restrict__ bz,
    const float* __restrict__ Wr, const float* __restrict__ Ur, const float* __restrict__ br,
    const float* __restrict__ Wh, const float* __restrict__ Uh, const float* __restrict__ bh)
{
    __shared__ float xT[64 * 64], hT[64 * 64], rT[64 * 64];   // 48KB
    int tx = threadIdx.x;
    int base = blockIdx.x * 64;
    int cg = tx & 15, rg = tx >> 4;
    int c0 = cg * 4, r0 = rg * 4;

    #pragma unroll
    for (int off = 0; off < 4; ++off) {
        int flat = off * 256 + tx;     // float4 idx, 1024/tile
        int r = flat >> 4;
        int g = base + r;
        float4 vx = (g < BN_) ? ((const float4*)x)[(size_t)g * 16 + (flat & 15)]
                              : make_float4(0.f, 0.f, 0.f, 0.f);
        float4 vh = (g < BN_) ? ((const float4*)h)[(size_t)g * 16 + (flat & 15)]
                              : make_float4(0.f, 0.f, 0.f, 0.f);
        ((float4*)xT)[flat] = vx;
        ((float4*)hT)[flat] = vh;
    }
    __syncthreads();

    bool okr[4];
    #pragma unroll
    for (int k = 0; k < 4; ++k) okr[k] = (base + r0 + k) < BN_;

    // z / r gates
    float az[4][4] = {}, ar[4][4] = {};
    mm_2a(xT, hT, Wz, Uz, r0, c0, az);
    mm_2a(xT, hT, Wr, Ur, r0, c0, ar);

    float4 bzv = *(const float4*)&bz[c0];
    float4 brv = *(const float4*)&br[c0];
    float zg[4][4];
    #pragma unroll
    for (int k = 0; k < 4; ++k) {
        float bzs[4] = {bzv.x, bzv.y, bzv.z, bzv.w};
        float brs[4] = {brv.x, brv.y, brv.z, brv.w};
        float4 hv = *(const float4*)&hT[(r0 + k) * 64 + c0];
        float hs[4] = {hv.x, hv.y, hv.z, hv.w};
        float rh[4];
        #pragma unroll
        for (int j = 0; j < 4; ++j) {
            zg[k][j] = 1.f / (1.f + expf(-(az[k][j] + bzs[j])));
            float rr = 1.f / (1.f + expf(-(ar[k][j] + brs[j])));
            rh[j] = rr * hs[j];
        }
        *(float4*)&rT[(r0 + k) * 64 + c0] = make_float4(rh[0], rh[1], rh[2], rh[3]);
    }
    __syncthreads();

    // hh = tanh(x@Wh + rh@Uh + bh); h' = (1-z)h + z*hh
    float ah[4][4] = {};
    mm_2a(xT, rT, Wh, Uh, r0, c0, ah);
    float4 bhv = *(const float4*)&bh[c0];
    #pragma unroll
    for (int k = 0; k < 4; ++k) {
        if (!okr[k]) continue;
        float bhs[4] = {bhv.x, bhv.y, bhv.z, bhv.w};
        float4 hv = *(const float4*)&hT[(r0 + k) * 64 + c0];
        float hs[4] = {hv.x, hv.y, hv.z, hv.w};
        float o[4];
        #pragma unroll
        for (int j = 0; j < 4; ++j) {
            float hh = tanhf(ah[k][j] + bhs[j]);
            o[j] = (1.f - zg[k][j]) * hs[j] + zg[k][j] * hh;
        }
        *(float4*)&h[(size_t)(base + r0 + k) * 64 + c0] = make_float4(o[0], o[1], o[2], o[3]);
    }
}

// ---------------- edge projection ------------------------------------------
__global__ __launch_bounds__(256) void k_edgeproj(
    const float* __restrict__ h, const float* __restrict__ W1,
    float* __restrict__ P)
{
    int wave = threadIdx.x >> 6;
    int lane = threadIdx.x & 63;
    int node = blockIdx.x * 4 + wave;      // < 20000

    float hval = h[(size_t)node * D_ + lane];
    const float* wp = (lane < 32) ? (W1 + lane) : (W1 + 64 * 32 + (lane - 32));
    float acc = 0.f;
    #pragma unroll 8
    for (int i = 0; i < D_; ++i)
        acc = fmaf(__shfl(hval, i, 64), wp[i * 32], acc);
    P[(size_t)node * D_ + lane] = acc;
}

// ---------------- edge decoder (light) --------------------------------------
__global__ __launch_bounds__(256) void k_decoder2(
    const float* __restrict__ P, const int* __restrict__ adj,
    const float* __restrict__ b1, const float* __restrict__ W2,
    const float* __restrict__ b2, const int* __restrict__ num_nodes,
    float* __restrict__ nw)
{
    int half = threadIdx.x >> 5;   // 0..7
    int j    = threadIdx.x & 31;
    float bias = b1[j], w2 = W2[j], b2v = b2[0];

    #pragma unroll 1
    for (int p = 0; p < 16; ++p) {
        int e = blockIdx.x * 128 + p * 8 + half;  // edge id < 320000
        int node = e >> 4;                        // b*N+n
        int b = node / N_;
        int a = adj[e];
        int pad = num_nodes[b];
        float own = P[(size_t)node * D_ + j];
        bool pd = (a == pad);
        float nbr = pd ? 0.f : P[((size_t)b * N_ + a) * D_ + 32 + j];
        float am = pd ? 0.f : 1.f;
        float t = tanhf(bias + am * own + nbr);
        float part = t * w2;
        #pragma unroll
        for (int m = 1; m < 32; m <<= 1) part += __shfl_xor(part, m, 64);
        if (j == 0) nw[e] = part + b2v;
    }
}

// ---------------- dual vars (per node scalar) + dual_demand -----------------
__global__ __launch_bounds__(256) void k_dualvars(
    const float* __restrict__ h, const float* __restrict__ W1,
    const float* __restrict__ b1, const float* __restrict__ W2,
    const float* __restrict__ b2, const float* __restrict__ demands,
    const int* __restrict__ num_nodes,
    float* __restrict__ dv, float* __restrict__ acc_out)
{
    __shared__ float sW1[D_ * 32];
    __shared__ float sW2[32];
    __shared__ float sPart[8];
    for (int i = threadIdx.x; i < D_ * 32; i += 256) sW1[i] = W1[i];
    if (threadIdx.x < 32) sW2[threadIdx.x] = W2[threadIdx.x];
    __syncthreads();

    int half = threadIdx.x >> 5;
    int j    = threadIdx.x & 31;
    int b = (blockIdx.x * 40) / N_;
    float bias = b1[j], b2v = b2[0];
    float local = 0.f;

    #pragma unroll 1
    for (int p = 0; p < 5; ++p) {
        int node = blockIdx.x * 40 + p * 8 + half;    // < 20000
        const float* hp = h + (size_t)node * D_;
        float h0 = hp[j], h1 = hp[j + 32];
        float acc = bias;
        #pragma unroll 8
        for (int i = 0; i < 32; ++i) {
            acc = fmaf(__shfl(h0, i, 32), sW1[i * 32 + j],        acc);
            acc = fmaf(__shfl(h1, i, 32), sW1[(i + 32) * 32 + j], acc);
        }
        float t = tanhf(acc);
        float part = t * sW2[j];
        #pragma unroll
        for (int m = 1; m < 32; m <<= 1) part += __shfl_xor(part, m, 64);
        if (j == 0) {
            float v = part + b2v;
            dv[node] = v;
            local += v * demands[node];
        }
    }
    if (j == 0) sPart[half] = local;
    __syncthreads();
    if (threadIdx.x == 0) {
        float s = 0.f;
        #pragma unroll
        for (int i = 0; i < 8; ++i) s += sPart[i];
        atomicAdd(&acc_out[(b * 3 + 2) * 16], s);
    }
}

// ---------------- dest softmax over permuted groups -------------------------
__global__ void k_dest(
    const float* __restrict__ nw, const int* __restrict__ in_idx,
    const int* __restrict__ inv_adj, const int* __restrict__ num_nodes,
    float* __restrict__ dest)
{
    int t = blockIdx.x * 256 + threadIdx.x;
    if (t >= BN_) return;
    int b = t / N_;
    int pad = num_nodes[b];
    float vals[K_]; float mx = -INFINITY;
    #pragma unroll
    for (int k = 0; k < K_; ++k) {
        int jj = in_idx[(size_t)t * K_ + k];
        float g = nw[(size_t)b * NK_ + jj];
        float im = (inv_adj[(size_t)t * K_ + k] == pad) ? 1.f : 0.f;
        float v = g - BIG_ * im;
        vals[k] = v; mx = fmaxf(mx, v);
    }
    float s = 0.f;
    #pragma unroll
    for (int k = 0; k < K_; ++k) { vals[k] = expf(vals[k] - mx); s += vals[k]; }
    float invs = 1.f / s;
    #pragma unroll
    for (int k = 0; k < K_; ++k) dest[(size_t)t * K_ + k] = vals[k] * invs;
}

// ---------------- normalized_weights + flow0 --------------------------------
__global__ void k_normw(
    const float* __restrict__ nw, const float* __restrict__ dest,
    const int* __restrict__ rev, const int* __restrict__ adj,
    const int* __restrict__ num_nodes, const float* __restrict__ demands,
    float* __restrict__ normw, float* __restrict__ flow0)
{
    int t = blockIdx.x * 256 + threadIdx.x;
    if (t >= BN_) return;
    int b = t / N_;
    int pad = num_nodes[b];
    float vals[K_]; float mx = -INFINITY;
    #pragma unroll
    for (int k = 0; k < K_; ++k) {
        size_t e = (size_t)t * K_ + k;
        float v = nw[e] * dest[(size_t)b * NK_ + rev[e]];
        float m = (adj[e] == pad) ? 1.f : 0.f;
        v -= BIG_ * m;
        vals[k] = v; mx = fmaxf(mx, v);
    }
    float s = 0.f;
    #pragma unroll
    for (int k = 0; k < K_; ++k) { vals[k] = expf(vals[k] - mx); s += vals[k]; }
    float invs = 1.f / s;
    float supply = fmaxf(-demands[t], 0.f);
    #pragma unroll
    for (int k = 0; k < K_; ++k) {
        float w = vals[k] * invs;
        normw[(size_t)t * K_ + k] = w;
        flow0[(size_t)t * K_ + k] = w * supply;
    }
}

// ---------------- one MCF flow step -----------------------------------------
__global__ void k_flow(
    const float* __restrict__ cur, const float* __restrict__ normw,
    const int* __restrict__ in_idx, const int* __restrict__ inv_adj,
    const int* __restrict__ num_nodes, const float* __restrict__ demands,
    float* __restrict__ nxt)
{
    int t = blockIdx.x * 256 + threadIdx.x;
    if (t >= BN_) return;
    int b = t / N_;
    int pad = num_nodes[b];
    float inflow = 0.f;
    #pragma unroll
    for (int k = 0; k < K_; ++k) {
        size_t e = (size_t)t * K_ + k;
        if (inv_adj[e] != pad) inflow += cur[(size_t)b * NK_ + in_idx[e]];
    }
    float tot = inflow + fmaxf(-demands[t], 0.f);
    #pragma unroll
    for (int k = 0; k < K_; ++k)
        nxt[(size_t)t * K_ + k] = normw[(size_t)t * K_ + k] * tot;
}

// ---------------- dual iterations + both cost reductions (dd fused) ---------
__global__ __launch_bounds__(256) void k_dualred(
    const float* __restrict__ el, const float* __restrict__ dv,
    const int* __restrict__ adj, const int* __restrict__ num_nodes,
    const float* __restrict__ flow, float* __restrict__ acc_out)
{
    int b = blockIdx.y;
    int ein = blockIdx.x * 256 + threadIdx.x;
    float c0 = 0.f, c1 = 0.f;
    if (ein < NK_) {
        size_t e = (size_t)b * NK_ + ein;
        int pad = num_nodes[b];
        int node = b * N_ + (ein >> 4);
        int a = adj[e];
        float am = (a == pad) ? 0.f : 1.f;
        float dtr = (a == pad) ? 0.f : dv[(size_t)b * N_ + a];
        float d = dtr - am * dv[node];
        float l = el[e];
        float f = 0.f, ac = 0.f;
        #pragma unroll
        for (int it = 0; it < 10; ++it) {
            float g = 2.f * l * f + d;
            ac = 0.9f * ac + 0.01f * g;
            f = fmaxf(f - ac, 0.f) * am;
        }
        float fl = flow[e];
        c0 = l * fl * fl;          // flow_cost term
        c1 = l * f * f + d * f;    // dual flow term
    }
    #pragma unroll
    for (int m = 1; m < 64; m <<= 1) { c0 += __shfl_xor(c0, m, 64); c1 += __shfl_xor(c1, m, 64); }
    __shared__ float s0[4], s1[4];
    int wave = threadIdx.x >> 6, lane = threadIdx.x & 63;
    if (lane == 0) { s0[wave] = c0; s1[wave] = c1; }
    __syncthreads();
    if (threadIdx.x == 0) {
        atomicAdd(&acc_out[(b * 3 + 0) * 16], s0[0] + s0[1] + s0[2] + s0[3]);
        atomicAdd(&acc_out[(b * 3 + 1) * 16], s1[0] + s1[1] + s1[2] + s1[3]);
    }
}

// ---------------- finalize --------------------------------------------------
__global__ void k_final(const float* __restrict__ acc, float* __restrict__ out) {
    int b = threadIdx.x;
    if (b < B_)
        out[b] = acc[(b * 3 + 0) * 16] - acc[(b * 3 + 1) * 16] + acc[(b * 3 + 2) * 16];
}

extern "C" void kernel_launch(void* const* d_in, const int* in_sizes, int n_in,
                              void* d_out, int out_size, void* d_ws, size_t ws_size,
                              hipStream_t stream)
{
    const float* demands = (const float*)d_in[0];
    const float* feat    = (const float*)d_in[1];
    const float* el      = (const float*)d_in[2];
    const float* embed   = (const float*)d_in[3];
    const float* encW    = (const float*)d_in[4];
    const float* encb    = (const float*)d_in[5];
    const float* nbW     = (const float*)d_in[6];
    const float* Wq      = (const float*)d_in[7];
    const float* Wk      = (const float*)d_in[8];
    const float* Wv      = (const float*)d_in[9];
    const float* Wo      = (const float*)d_in[10];
    const float* gWz     = (const float*)d_in[11];
    const float* gUz     = (const float*)d_in[12];
    const float* gbz     = (const float*)d_in[13];
    const float* gWr     = (const float*)d_in[14];
    const float* gUr     = (const float*)d_in[15];
    const float* gbr     = (const float*)d_in[16];
    const float* gWh     = (const float*)d_in[17];
    const float* gUh     = (const float*)d_in[18];
    const float* gbh     = (const float*)d_in[19];
    const float* decW1   = (const float*)d_in[20];
    const float* decb1   = (const float*)d_in[21];
    const float* decW2   = (const float*)d_in[22];
    const float* decb2   = (const float*)d_in[23];
    const float* dualW1  = (const float*)d_in[24];
    const float* dualb1  = (const float*)d_in[25];
    const float* dualW2  = (const float*)d_in[26];
    const float* dualb2  = (const float*)d_in[27];
    const int* adj       = (const int*)d_in[28];
    const int* invadj    = (const int*)d_in[29];
    const int* neigh     = (const int*)d_in[30];
    const int* inidx     = (const int*)d_in[31];
    const int* revidx    = (const int*)d_in[32];
    const int* numn      = (const int*)d_in[33];

    // workspace (floats), total ~4.2M f = 16.8 MB
    float* ws    = (float*)d_ws;
    float* h     = ws;                   // 1,280,000
    float* x     = ws + 1280000;         // 1,280,000 (x; later P)
    float* fb    = ws + 2560000;         // flow region
    float* nw    = fb;                   // 320,000
    float* dest  = fb + 320000;          // 320,000
    float* normw = fb + 640000;          // 320,000
    float* flowA = fb + 960000;          // 320,000
    float* flowB = fb + 1280000;         // 320,000
    float* dv    = fb + 1600000;         // 20,000
    float* P     = x;                    // reuse (x dead after layers)
    float* acc   = ws + 4200000;         // 192

    const int GBT = (BN_ + 63) / 64;     // 313 node-tiles

    k_zero<<<1, 256, 0, stream>>>(acc);
    k_encode<<<BN_ / 4, 256, 0, stream>>>(embed, feat, encW, encb, h);

    for (int layer = 0; layer < 2; ++layer) {
        k_layerA<<<GBT, 256, 0, stream>>>(h, neigh, numn, nbW, Wq, Wk, Wv, Wo, x);
        k_layerB<<<GBT, 256, 0, stream>>>(x, h, gWz, gUz, gbz, gWr, gUr, gbr,
                                          gWh, gUh, gbh);
    }

    k_edgeproj<<<BN_ / 4, 256, 0, stream>>>(h, decW1, P);
    k_decoder2<<<(B_ * NK_) / 128, 256, 0, stream>>>(P, adj, decb1, decW2, decb2, numn, nw);
    k_dualvars<<<BN_ / 40, 256, 0, stream>>>(h, dualW1, dualb1, dualW2, dualb2, demands, numn, dv, acc);
    k_dest<<<(BN_ + 255) / 256, 256, 0, stream>>>(nw, inidx, invadj, numn, dest);
    k_normw<<<(BN_ + 255) / 256, 256, 0, stream>>>(nw, dest, revidx, adj, numn, demands, normw, flowA);

    float* cur = flowA; float* nxt = flowB;
    for (int it = 0; it < 10; ++it) {
        k_flow<<<(BN_ + 255) / 256, 256, 0, stream>>>(cur, normw, inidx, invadj, numn, demands, nxt);
        float* tmp = cur; cur = nxt; nxt = tmp;
    }

    dim3 gred((NK_ + 255) / 256, B_);
    k_dualred<<<gred, 256, 0, stream>>>(el, dv, adj, numn, cur, acc);
    k_final<<<1, 64, 0, stream>>>(acc, (float*)d_out);
}

// Round 6
// 621.557 us; speedup vs baseline: 1.5360x; 1.5360x over previous
//
#include <hip/hip_runtime.h>
#include <math.h>

#define B_ 4
#define N_ 5000
#define K_ 16
#define L_ 3
#define F_ 2
#define E_ 32
#define D_ 64
#define H_ 4
#define BN_ (B_*N_)          /* 20000 */
#define NK_ (N_*K_)          /* 80000 */
#define BIG_ 1.0e9f
#define RS_ 68               /* padded LDS row stride (floats) */

// ---------------- zero the accumulators -------------------------------------
__global__ void k_zero(float* __restrict__ acc) {
    if (threadIdx.x < 192) acc[threadIdx.x] = 0.f;
}

// ---------------- encoder: h = [emb_norm, feat] @ enc_W + enc_b -------------
__global__ __launch_bounds__(256) void k_encode(
    const float* __restrict__ embed, const float* __restrict__ feat,
    const float* __restrict__ encW, const float* __restrict__ encb,
    float* __restrict__ h)
{
    int wave = threadIdx.x >> 6;
    int lane = threadIdx.x & 63;
    int node = blockIdx.x * 4 + wave;      // b*N+n  in [0,20000)
    int n = node % N_;

    float e = (lane < E_) ? embed[(size_t)n * E_ + lane] : 0.f;
    float ss = e * e;
    #pragma unroll
    for (int m = 32; m >= 1; m >>= 1) ss += __shfl_xor(ss, m, 64);
    float scale = 1.f / fmaxf(sqrtf(ss), 1.f);

    float inval = (lane < E_) ? e * scale
                : (lane < E_ + F_) ? feat[(size_t)node * F_ + (lane - E_)]
                : 0.f;

    float acc = encb[lane];
    #pragma unroll
    for (int i = 0; i < E_ + F_; ++i)
        acc = fmaf(__shfl(inval, i, 64), encW[i * D_ + lane], acc);
    h[(size_t)node * D_ + lane] = acc;
}

// ---------- per-thread row GEMM helpers: 1 row (from LDS) x 4 cols ----------
__device__ __forceinline__ void mmrow_g(
    const float* Arow, const float* __restrict__ W, int c0, float acc[4])
{
    #pragma unroll 4
    for (int i = 0; i < 64; i += 4) {
        float4 a = *(const float4*)&Arow[i];
        #pragma unroll
        for (int ii = 0; ii < 4; ++ii) {
            float av = (ii == 0) ? a.x : (ii == 1) ? a.y : (ii == 2) ? a.z : a.w;
            float4 w = *(const float4*)&W[(i + ii) * 64 + c0];
            acc[0] = fmaf(av, w.x, acc[0]);
            acc[1] = fmaf(av, w.y, acc[1]);
            acc[2] = fmaf(av, w.z, acc[2]);
            acc[3] = fmaf(av, w.w, acc[3]);
        }
    }
}

__device__ __forceinline__ void mmrow_kv(
    const float* Arow, const float* __restrict__ Wk, const float* __restrict__ Wv,
    int c0, float ak[4], float av[4])
{
    #pragma unroll 4
    for (int i = 0; i < 64; i += 4) {
        float4 a = *(const float4*)&Arow[i];
        #pragma unroll
        for (int ii = 0; ii < 4; ++ii) {
            float aa = (ii == 0) ? a.x : (ii == 1) ? a.y : (ii == 2) ? a.z : a.w;
            float4 wk = *(const float4*)&Wk[(i + ii) * 64 + c0];
            float4 wv = *(const float4*)&Wv[(i + ii) * 64 + c0];
            ak[0] = fmaf(aa, wk.x, ak[0]);
            ak[1] = fmaf(aa, wk.y, ak[1]);
            ak[2] = fmaf(aa, wk.z, ak[2]);
            ak[3] = fmaf(aa, wk.w, ak[3]);
            av[0] = fmaf(aa, wv.x, av[0]);
            av[1] = fmaf(aa, wv.y, av[1]);
            av[2] = fmaf(aa, wv.z, av[2]);
            av[3] = fmaf(aa, wv.w, av[3]);
        }
    }
}

// ================= fully fused graph layer ==================================
// 16 nodes/block, 256 threads: thread = (row = tx>>4, cols c0=4*(tx&15)).
// Every LDS tile row is touched only by its own wave -> no barriers needed
// after the initial nbW staging (same-wave LDS ops are in-order).
__global__ __launch_bounds__(256, 4) void k_layer(
    const float* __restrict__ hin, float* __restrict__ hout,
    const int* __restrict__ neigh, const int* __restrict__ numn,
    const float* __restrict__ nbW, const float* __restrict__ Wq,
    const float* __restrict__ Wk, const float* __restrict__ Wv,
    const float* __restrict__ Wo,
    const float* __restrict__ gWz, const float* __restrict__ gUz, const float* __restrict__ gbz,
    const float* __restrict__ gWr, const float* __restrict__ gUr, const float* __restrict__ gbr,
    const float* __restrict__ gWh, const float* __restrict__ gUh, const float* __restrict__ gbh)
{
    __shared__ float sW[64 * 64];           // nbW (16KB)
    __shared__ float sA[16 * RS_];          // mean -> states -> ao -> rh
    __shared__ float sX[16 * RS_];          // x tile
    __shared__ float sH[16 * RS_];          // h tile
    __shared__ int   sIdx[256];             // [k][row] transposed

    int tx = threadIdx.x;
    int row = tx >> 4, cg = tx & 15, c0 = cg * 4;
    int g = blockIdx.x * 16 + row;          // node id (grid exact: 1250*16=20000)
    int b = g / N_;
    int pad = numn[b];
    const float4* hb4 = (const float4*)(hin + (size_t)b * N_ * D_);

    #pragma unroll
    for (int i = tx; i < 1024; i += 256)
        ((float4*)sW)[i] = ((const float4*)nbW)[i];
    *(float4*)&sH[row * RS_ + c0] = *(const float4*)&hin[(size_t)g * 64 + c0];
    __syncthreads();

    // q = h_row @ Wq
    float qv[4] = {0.f, 0.f, 0.f, 0.f};
    mmrow_g(&sH[row * RS_], Wq, c0, qv);

    float av[3][4];
    float p[3];

    #pragma unroll 1
    for (int t = 0; t < 3; ++t) {
        // stage neighbor ids (transposed: [k][row] -> bank-clean reads)
        sIdx[cg * 16 + row] = neigh[((size_t)t * BN_ + g) * K_ + cg];
        // gather-mean: this thread sums its 4 cols over valid neighbors
        float4 s = make_float4(0.f, 0.f, 0.f, 0.f);
        int cnt = 0;
        #pragma unroll
        for (int k = 0; k < K_; ++k) {
            int idx = sIdx[k * 16 + row];
            if (idx != pad) {
                float4 v = hb4[(size_t)idx * 16 + cg];
                s.x += v.x; s.y += v.y; s.z += v.z; s.w += v.w;
                cnt++;
            }
        }
        float inv = 1.f / fmaxf((float)cnt, 1.f);
        *(float4*)&sA[row * RS_ + c0] = make_float4(s.x * inv, s.y * inv, s.z * inv, s.w * inv);

        // states = tanh(mean @ nbW)
        float sr[4] = {0.f, 0.f, 0.f, 0.f};
        mmrow_g(&sA[row * RS_], sW, c0, sr);
        *(float4*)&sA[row * RS_ + c0] =
            make_float4(tanhf(sr[0]), tanhf(sr[1]), tanhf(sr[2]), tanhf(sr[3]));

        // kk, vv
        float ak[4] = {0.f, 0.f, 0.f, 0.f};
        av[t][0] = av[t][1] = av[t][2] = av[t][3] = 0.f;
        mmrow_kv(&sA[row * RS_], Wk, Wv, c0, ak, av[t]);

        // per-head score: sum q*kk over 16 cols = 4 threads (cg quad)
        float pp = ak[0] * qv[0] + ak[1] * qv[1] + ak[2] * qv[2] + ak[3] * qv[3];
        pp += __shfl_xor(pp, 1, 64);
        pp += __shfl_xor(pp, 2, 64);
        p[t] = pp * 0.25f;                  // / sqrt(dh=16)
    }

    // softmax over t; ao = sum w_t * vv_t
    float mx = fmaxf(p[0], fmaxf(p[1], p[2]));
    float e0 = expf(p[0] - mx), e1 = expf(p[1] - mx), e2 = expf(p[2] - mx);
    float winv = 1.f / (e0 + e1 + e2);
    float w0 = e0 * winv, w1 = e1 * winv, w2 = e2 * winv;
    *(float4*)&sX[row * RS_ + c0] = make_float4(
        w0 * av[0][0] + w1 * av[1][0] + w2 * av[2][0],
        w0 * av[0][1] + w1 * av[1][1] + w2 * av[2][1],
        w0 * av[0][2] + w1 * av[1][2] + w2 * av[2][2],
        w0 * av[0][3] + w1 * av[1][3] + w2 * av[2][3]);

    // x = tanh(ao @ Wo)  (read full row, then overwrite own cols)
    float xr[4] = {0.f, 0.f, 0.f, 0.f};
    mmrow_g(&sX[row * RS_], Wo, c0, xr);
    *(float4*)&sX[row * RS_ + c0] =
        make_float4(tanhf(xr[0]), tanhf(xr[1]), tanhf(xr[2]), tanhf(xr[3]));

    // GRU gates
    float az[4] = {0.f, 0.f, 0.f, 0.f}, ar[4] = {0.f, 0.f, 0.f, 0.f};
    mmrow_g(&sX[row * RS_], gWz, c0, az);
    mmrow_g(&sH[row * RS_], gUz, c0, az);
    mmrow_g(&sX[row * RS_], gWr, c0, ar);
    mmrow_g(&sH[row * RS_], gUr, c0, ar);
    float4 bzv = *(const float4*)&gbz[c0];
    float4 brv = *(const float4*)&gbr[c0];
    float4 hv = *(const float4*)&sH[row * RS_ + c0];
    float z[4], rr[4];
    z[0] = 1.f / (1.f + expf(-(az[0] + bzv.x)));
    z[1] = 1.f / (1.f + expf(-(az[1] + bzv.y)));
    z[2] = 1.f / (1.f + expf(-(az[2] + bzv.z)));
    z[3] = 1.f / (1.f + expf(-(az[3] + bzv.w)));
    rr[0] = 1.f / (1.f + expf(-(ar[0] + brv.x)));
    rr[1] = 1.f / (1.f + expf(-(ar[1] + brv.y)));
    rr[2] = 1.f / (1.f + expf(-(ar[2] + brv.z)));
    rr[3] = 1.f / (1.f + expf(-(ar[3] + brv.w)));
    *(float4*)&sA[row * RS_ + c0] =
        make_float4(rr[0] * hv.x, rr[1] * hv.y, rr[2] * hv.z, rr[3] * hv.w);

    float ah[4] = {0.f, 0.f, 0.f, 0.f};
    mmrow_g(&sX[row * RS_], gWh, c0, ah);
    mmrow_g(&sA[row * RS_], gUh, c0, ah);
    float4 bhv = *(const float4*)&gbh[c0];
    float o0 = (1.f - z[0]) * hv.x + z[0] * tanhf(ah[0] + bhv.x);
    float o1 = (1.f - z[1]) * hv.y + z[1] * tanhf(ah[1] + bhv.y);
    float o2 = (1.f - z[2]) * hv.z + z[2] * tanhf(ah[2] + bhv.z);
    float o3 = (1.f - z[3]) * hv.w + z[3] * tanhf(ah[3] + bhv.w);
    *(float4*)&hout[(size_t)g * 64 + c0] = make_float4(o0, o1, o2, o3);
}

// ---------------- edge projection ------------------------------------------
__global__ __launch_bounds__(256) void k_edgeproj(
    const float* __restrict__ h, const float* __restrict__ W1,
    float* __restrict__ P)
{
    int wave = threadIdx.x >> 6;
    int lane = threadIdx.x & 63;
    int node = blockIdx.x * 4 + wave;      // < 20000

    float hval = h[(size_t)node * D_ + lane];
    const float* wp = (lane < 32) ? (W1 + lane) : (W1 + 64 * 32 + (lane - 32));
    float acc = 0.f;
    #pragma unroll 8
    for (int i = 0; i < D_; ++i)
        acc = fmaf(__shfl(hval, i, 64), wp[i * 32], acc);
    P[(size_t)node * D_ + lane] = acc;
}

// ---------------- edge decoder (light) --------------------------------------
__global__ __launch_bounds__(256) void k_decoder2(
    const float* __restrict__ P, const int* __restrict__ adj,
    const float* __restrict__ b1, const float* __restrict__ W2,
    const float* __restrict__ b2, const int* __restrict__ num_nodes,
    float* __restrict__ nw)
{
    int half = threadIdx.x >> 5;   // 0..7
    int j    = threadIdx.x & 31;
    float bias = b1[j], w2 = W2[j], b2v = b2[0];

    #pragma unroll 1
    for (int p = 0; p < 16; ++p) {
        int e = blockIdx.x * 128 + p * 8 + half;  // edge id < 320000
        int node = e >> 4;                        // b*N+n
        int b = node / N_;
        int a = adj[e];
        int pad = num_nodes[b];
        float own = P[(size_t)node * D_ + j];
        bool pd = (a == pad);
        float nbr = pd ? 0.f : P[((size_t)b * N_ + a) * D_ + 32 + j];
        float am = pd ? 0.f : 1.f;
        float t = tanhf(bias + am * own + nbr);
        float part = t * w2;
        #pragma unroll
        for (int m = 1; m < 32; m <<= 1) part += __shfl_xor(part, m, 64);
        if (j == 0) nw[e] = part + b2v;
    }
}

// ---------------- dual vars (per node scalar) + dual_demand -----------------
__global__ __launch_bounds__(256) void k_dualvars(
    const float* __restrict__ h, const float* __restrict__ W1,
    const float* __restrict__ b1, const float* __restrict__ W2,
    const float* __restrict__ b2, const float* __restrict__ demands,
    const int* __restrict__ num_nodes,
    float* __restrict__ dv, float* __restrict__ acc_out)
{
    __shared__ float sW1[D_ * 32];
    __shared__ float sW2[32];
    __shared__ float sPart[8];
    for (int i = threadIdx.x; i < D_ * 32; i += 256) sW1[i] = W1[i];
    if (threadIdx.x < 32) sW2[threadIdx.x] = W2[threadIdx.x];
    __syncthreads();

    int half = threadIdx.x >> 5;
    int j    = threadIdx.x & 31;
    int b = (blockIdx.x * 40) / N_;
    float bias = b1[j], b2v = b2[0];
    float local = 0.f;

    #pragma unroll 1
    for (int p = 0; p < 5; ++p) {
        int node = blockIdx.x * 40 + p * 8 + half;    // < 20000
        const float* hp = h + (size_t)node * D_;
        float h0 = hp[j], h1 = hp[j + 32];
        float acc = bias;
        #pragma unroll 8
        for (int i = 0; i < 32; ++i) {
            acc = fmaf(__shfl(h0, i, 32), sW1[i * 32 + j],        acc);
            acc = fmaf(__shfl(h1, i, 32), sW1[(i + 32) * 32 + j], acc);
        }
        float t = tanhf(acc);
        float part = t * sW2[j];
        #pragma unroll
        for (int m = 1; m < 32; m <<= 1) part += __shfl_xor(part, m, 64);
        if (j == 0) {
            float v = part + b2v;
            dv[node] = v;
            local += v * demands[node];
        }
    }
    if (j == 0) sPart[half] = local;
    __syncthreads();
    if (threadIdx.x == 0) {
        float s = 0.f;
        #pragma unroll
        for (int i = 0; i < 8; ++i) s += sPart[i];
        atomicAdd(&acc_out[(b * 3 + 2) * 16], s);
    }
}

// ---------------- dest softmax over permuted groups -------------------------
__global__ void k_dest(
    const float* __restrict__ nw, const int* __restrict__ in_idx,
    const int* __restrict__ inv_adj, const int* __restrict__ num_nodes,
    float* __restrict__ dest)
{
    int t = blockIdx.x * 256 + threadIdx.x;
    if (t >= BN_) return;
    int b = t / N_;
    int pad = num_nodes[b];
    float vals[K_]; float mx = -INFINITY;
    #pragma unroll
    for (int k = 0; k < K_; ++k) {
        int jj = in_idx[(size_t)t * K_ + k];
        float g = nw[(size_t)b * NK_ + jj];
        float im = (inv_adj[(size_t)t * K_ + k] == pad) ? 1.f : 0.f;
        float v = g - BIG_ * im;
        vals[k] = v; mx = fmaxf(mx, v);
    }
    float s = 0.f;
    #pragma unroll
    for (int k = 0; k < K_; ++k) { vals[k] = expf(vals[k] - mx); s += vals[k]; }
    float invs = 1.f / s;
    #pragma unroll
    for (int k = 0; k < K_; ++k) dest[(size_t)t * K_ + k] = vals[k] * invs;
}

// ---------------- normalized_weights + flow0 --------------------------------
__global__ void k_normw(
    const float* __restrict__ nw, const float* __restrict__ dest,
    const int* __restrict__ rev, const int* __restrict__ adj,
    const int* __restrict__ num_nodes, const float* __restrict__ demands,
    float* __restrict__ normw, float* __restrict__ flow0)
{
    int t = blockIdx.x * 256 + threadIdx.x;
    if (t >= BN_) return;
    int b = t / N_;
    int pad = num_nodes[b];
    float vals[K_]; float mx = -INFINITY;
    #pragma unroll
    for (int k = 0; k < K_; ++k) {
        size_t e = (size_t)t * K_ + k;
        float v = nw[e] * dest[(size_t)b * NK_ + rev[e]];
        float m = (adj[e] == pad) ? 1.f : 0.f;
        v -= BIG_ * m;
        vals[k] = v; mx = fmaxf(mx, v);
    }
    float s = 0.f;
    #pragma unroll
    for (int k = 0; k < K_; ++k) { vals[k] = expf(vals[k] - mx); s += vals[k]; }
    float invs = 1.f / s;
    float supply = fmaxf(-demands[t], 0.f);
    #pragma unroll
    for (int k = 0; k < K_; ++k) {
        float w = vals[k] * invs;
        normw[(size_t)t * K_ + k] = w;
        flow0[(size_t)t * K_ + k] = w * supply;
    }
}

// ---------------- one MCF flow step -----------------------------------------
__global__ void k_flow(
    const float* __restrict__ cur, const float* __restrict__ normw,
    const int* __restrict__ in_idx, const int* __restrict__ inv_adj,
    const int* __restrict__ num_nodes, const float* __restrict__ demands,
    float* __restrict__ nxt)
{
    int t = blockIdx.x * 256 + threadIdx.x;
    if (t >= BN_) return;
    int b = t / N_;
    int pad = num_nodes[b];
    float inflow = 0.f;
    #pragma unroll
    for (int k = 0; k < K_; ++k) {
        size_t e = (size_t)t * K_ + k;
        if (inv_adj[e] != pad) inflow += cur[(size_t)b * NK_ + in_idx[e]];
    }
    float tot = inflow + fmaxf(-demands[t], 0.f);
    #pragma unroll
    for (int k = 0; k < K_; ++k)
        nxt[(size_t)t * K_ + k] = normw[(size_t)t * K_ + k] * tot;
}

// ---------------- dual iterations + both cost reductions (dd fused) ---------
__global__ __launch_bounds__(256) void k_dualred(
    const float* __restrict__ el, const float* __restrict__ dv,
    const int* __restrict__ adj, const int* __restrict__ num_nodes,
    const float* __restrict__ flow, float* __restrict__ acc_out)
{
    int b = blockIdx.y;
    int ein = blockIdx.x * 256 + threadIdx.x;
    float c0 = 0.f, c1 = 0.f;
    if (ein < NK_) {
        size_t e = (size_t)b * NK_ + ein;
        int pad = num_nodes[b];
        int node = b * N_ + (ein >> 4);
        int a = adj[e];
        float am = (a == pad) ? 0.f : 1.f;
        float dtr = (a == pad) ? 0.f : dv[(size_t)b * N_ + a];
        float d = dtr - am * dv[node];
        float l = el[e];
        float f = 0.f, ac = 0.f;
        #pragma unroll
        for (int it = 0; it < 10; ++it) {
            float g = 2.f * l * f + d;
            ac = 0.9f * ac + 0.01f * g;
            f = fmaxf(f - ac, 0.f) * am;
        }
        float fl = flow[e];
        c0 = l * fl * fl;          // flow_cost term
        c1 = l * f * f + d * f;    // dual flow term
    }
    #pragma unroll
    for (int m = 1; m < 64; m <<= 1) { c0 += __shfl_xor(c0, m, 64); c1 += __shfl_xor(c1, m, 64); }
    __shared__ float s0[4], s1[4];
    int wave = threadIdx.x >> 6, lane = threadIdx.x & 63;
    if (lane == 0) { s0[wave] = c0; s1[wave] = c1; }
    __syncthreads();
    if (threadIdx.x == 0) {
        atomicAdd(&acc_out[(b * 3 + 0) * 16], s0[0] + s0[1] + s0[2] + s0[3]);
        atomicAdd(&acc_out[(b * 3 + 1) * 16], s1[0] + s1[1] + s1[2] + s1[3]);
    }
}

// ---------------- finalize --------------------------------------------------
__global__ void k_final(const float* __restrict__ acc, float* __restrict__ out) {
    int b = threadIdx.x;
    if (b < B_)
        out[b] = acc[(b * 3 + 0) * 16] - acc[(b * 3 + 1) * 16] + acc[(b * 3 + 2) * 16];
}

extern "C" void kernel_launch(void* const* d_in, const int* in_sizes, int n_in,
                              void* d_out, int out_size, void* d_ws, size_t ws_size,
                              hipStream_t stream)
{
    const float* demands = (const float*)d_in[0];
    const float* feat    = (const float*)d_in[1];
    const float* el      = (const float*)d_in[2];
    const float* embed   = (const float*)d_in[3];
    const float* encW    = (const float*)d_in[4];
    const float* encb    = (const float*)d_in[5];
    const float* nbW     = (const float*)d_in[6];
    const float* Wq      = (const float*)d_in[7];
    const float* Wk      = (const float*)d_in[8];
    const float* Wv      = (const float*)d_in[9];
    const float* Wo      = (const float*)d_in[10];
    const float* gWz     = (const float*)d_in[11];
    const float* gUz     = (const float*)d_in[12];
    const float* gbz     = (const float*)d_in[13];
    const float* gWr     = (const float*)d_in[14];
    const float* gUr     = (const float*)d_in[15];
    const float* gbr     = (const float*)d_in[16];
    const float* gWh     = (const float*)d_in[17];
    const float* gUh     = (const float*)d_in[18];
    const float* gbh     = (const float*)d_in[19];
    const float* decW1   = (const float*)d_in[20];
    const float* decb1   = (const float*)d_in[21];
    const float* decW2   = (const float*)d_in[22];
    const float* decb2   = (const float*)d_in[23];
    const float* dualW1  = (const float*)d_in[24];
    const float* dualb1  = (const float*)d_in[25];
    const float* dualW2  = (const float*)d_in[26];
    const float* dualb2  = (const float*)d_in[27];
    const int* adj       = (const int*)d_in[28];
    const int* invadj    = (const int*)d_in[29];
    const int* neigh     = (const int*)d_in[30];
    const int* inidx     = (const int*)d_in[31];
    const int* revidx    = (const int*)d_in[32];
    const int* numn      = (const int*)d_in[33];

    // workspace (floats)
    float* ws    = (float*)d_ws;
    float* h0    = ws;                   // 1,280,000
    float* h1    = ws + 1280000;         // 1,280,000 (ping-pong; P after layers)
    float* fb    = ws + 2560000;         // flow region
    float* nw    = fb;                   // 320,000
    float* dest  = fb + 320000;          // 320,000
    float* normw = fb + 640000;          // 320,000
    float* flowA = fb + 960000;          // 320,000
    float* flowB = fb + 1280000;         // 320,000
    float* dv    = fb + 1600000;         // 20,000
    float* P     = h1;                   // reuse (h1 dead after layer 1)
    float* acc   = ws + 4200000;         // 192

    k_zero<<<1, 256, 0, stream>>>(acc);
    k_encode<<<BN_ / 4, 256, 0, stream>>>(embed, feat, encW, encb, h0);

    // layer 0: h0 -> h1 ; layer 1: h1 -> h0  (gathers must read pre-layer h)
    k_layer<<<BN_ / 16, 256, 0, stream>>>(h0, h1, neigh, numn, nbW, Wq, Wk, Wv, Wo,
                                          gWz, gUz, gbz, gWr, gUr, gbr, gWh, gUh, gbh);
    k_layer<<<BN_ / 16, 256, 0, stream>>>(h1, h0, neigh, numn, nbW, Wq, Wk, Wv, Wo,
                                          gWz, gUz, gbz, gWr, gUr, gbr, gWh, gUh, gbh);
    float* h = h0;

    k_edgeproj<<<BN_ / 4, 256, 0, stream>>>(h, decW1, P);
    k_decoder2<<<(B_ * NK_) / 128, 256, 0, stream>>>(P, adj, decb1, decW2, decb2, numn, nw);
    k_dualvars<<<BN_ / 40, 256, 0, stream>>>(h, dualW1, dualb1, dualW2, dualb2, demands, numn, dv, acc);
    k_dest<<<(BN_ + 255) / 256, 256, 0, stream>>>(nw, inidx, invadj, numn, dest);
    k_normw<<<(BN_ + 255) / 256, 256, 0, stream>>>(nw, dest, revidx, adj, numn, demands, normw, flowA);

    float* cur = flowA; float* nxt = flowB;
    for (int it = 0; it < 10; ++it) {
        k_flow<<<(BN_ + 255) / 256, 256, 0, stream>>>(cur, normw, inidx, invadj, numn, demands, nxt);
        float* tmp = cur; cur = nxt; nxt = tmp;
    }

    dim3 gred((NK_ + 255) / 256, B_);
    k_dualred<<<gred, 256, 0, stream>>>(el, dv, adj, numn, cur, acc);
    k_final<<<1, 64, 0, stream>>>(acc, (float*)d_out);
}

// Round 7
// 521.303 us; speedup vs baseline: 1.8314x; 1.1923x over previous
//
#include <hip/hip_runtime.h>
#include <math.h>

#define B_ 4
#define N_ 5000
#define K_ 16
#define L_ 3
#define F_ 2
#define E_ 32
#define D_ 64
#define H_ 4
#define BN_ (B_*N_)          /* 20000 */
#define NK_ (N_*K_)          /* 80000 */
#define BIG_ 1.0e9f
#define RS_ 68               /* padded LDS row stride (floats) */

// ---------------- zero the accumulators -------------------------------------
__global__ void k_zero(float* __restrict__ acc) {
    if (threadIdx.x < 192) acc[threadIdx.x] = 0.f;
}

// ---------------- encoder: h = [emb_norm, feat] @ enc_W + enc_b -------------
__global__ __launch_bounds__(256) void k_encode(
    const float* __restrict__ embed, const float* __restrict__ feat,
    const float* __restrict__ encW, const float* __restrict__ encb,
    float* __restrict__ h)
{
    int wave = threadIdx.x >> 6;
    int lane = threadIdx.x & 63;
    int node = blockIdx.x * 4 + wave;      // b*N+n  in [0,20000)
    int n = node % N_;

    float e = (lane < E_) ? embed[(size_t)n * E_ + lane] : 0.f;
    float ss = e * e;
    #pragma unroll
    for (int m = 32; m >= 1; m >>= 1) ss += __shfl_xor(ss, m, 64);
    float scale = 1.f / fmaxf(sqrtf(ss), 1.f);

    float inval = (lane < E_) ? e * scale
                : (lane < E_ + F_) ? feat[(size_t)node * F_ + (lane - E_)]
                : 0.f;

    float acc = encb[lane];
    #pragma unroll
    for (int i = 0; i < E_ + F_; ++i)
        acc = fmaf(__shfl(inval, i, 64), encW[i * D_ + lane], acc);
    h[(size_t)node * D_ + lane] = acc;
}

// ---------- per-thread row GEMM helpers: 1 row x 4 cols (A, W in LDS) -------
__device__ __forceinline__ void mmrow_g(
    const float* Arow, const float* W, int c0, float acc[4])
{
    #pragma unroll 4
    for (int i = 0; i < 64; i += 4) {
        float4 a = *(const float4*)&Arow[i];
        #pragma unroll
        for (int ii = 0; ii < 4; ++ii) {
            float av = (ii == 0) ? a.x : (ii == 1) ? a.y : (ii == 2) ? a.z : a.w;
            float4 w = *(const float4*)&W[(i + ii) * 64 + c0];
            acc[0] = fmaf(av, w.x, acc[0]);
            acc[1] = fmaf(av, w.y, acc[1]);
            acc[2] = fmaf(av, w.z, acc[2]);
            acc[3] = fmaf(av, w.w, acc[3]);
        }
    }
}

__device__ __forceinline__ void mmrow_kv(
    const float* Arow, const float* Wk, const float* Wv,
    int c0, float ak[4], float av[4])
{
    #pragma unroll 4
    for (int i = 0; i < 64; i += 4) {
        float4 a = *(const float4*)&Arow[i];
        #pragma unroll
        for (int ii = 0; ii < 4; ++ii) {
            float aa = (ii == 0) ? a.x : (ii == 1) ? a.y : (ii == 2) ? a.z : a.w;
            float4 wk = *(const float4*)&Wk[(i + ii) * 64 + c0];
            float4 wv = *(const float4*)&Wv[(i + ii) * 64 + c0];
            ak[0] = fmaf(aa, wk.x, ak[0]);
            ak[1] = fmaf(aa, wk.y, ak[1]);
            ak[2] = fmaf(aa, wk.z, ak[2]);
            ak[3] = fmaf(aa, wk.w, ak[3]);
            av[0] = fmaf(aa, wv.x, av[0]);
            av[1] = fmaf(aa, wv.y, av[1]);
            av[2] = fmaf(aa, wv.z, av[2]);
            av[3] = fmaf(aa, wv.w, av[3]);
        }
    }
}

// cooperative 16KB weight stage: global -> LDS
__device__ __forceinline__ void stageW(float* dst, const float* __restrict__ src, int tx)
{
    #pragma unroll
    for (int i = tx; i < 1024; i += 256)
        ((float4*)dst)[i] = ((const float4*)src)[i];
}

// ================= fully fused graph layer (LDS-staged weights) =============
// 16 nodes/block, 256 threads: thread = (row = tx>>4, cols c0=4*(tx&15)).
// Weights stream through a 32KB double-slot LDS window, re-staged per phase.
// Tile rows are wave-local (4 rows/wave) -> no barriers needed except around
// weight re-staging (cross-wave LDS reuse).
__global__ __launch_bounds__(256, 4) void k_layer(
    const float* __restrict__ hin, float* __restrict__ hout,
    const int* __restrict__ neigh, const int* __restrict__ numn,
    const float* __restrict__ nbW, const float* __restrict__ Wq,
    const float* __restrict__ Wk, const float* __restrict__ Wv,
    const float* __restrict__ Wo,
    const float* __restrict__ gWz, const float* __restrict__ gUz, const float* __restrict__ gbz,
    const float* __restrict__ gWr, const float* __restrict__ gUr, const float* __restrict__ gbr,
    const float* __restrict__ gWh, const float* __restrict__ gUh, const float* __restrict__ gbh)
{
    __shared__ float wb0[64 * 64];          // 16KB W slot A
    __shared__ float wb1[64 * 64];          // 16KB W slot B
    __shared__ float sM[3][16 * RS_];       // mean->state tiles (12.75KB)
    __shared__ float sH[16 * RS_];          // h tile
    __shared__ float sX[16 * RS_];          // ao -> x tile
    __shared__ int   sIdx[3][256];          // neighbor ids, [t][k*16+row]

    int tx = threadIdx.x;
    int row = tx >> 4, cg = tx & 15, c0 = cg * 4;
    int g = blockIdx.x * 16 + row;          // node id (grid exact: 1250*16=20000)
    int b = g / N_;
    int pad = numn[b];
    const float4* hb4 = (const float4*)(hin + (size_t)b * N_ * D_);

    // ---- phase 0: stage Wq|nbW, h rows, neighbor ids ----
    stageW(wb0, Wq, tx);
    stageW(wb1, nbW, tx);
    *(float4*)&sH[row * RS_ + c0] = *(const float4*)&hin[(size_t)g * 64 + c0];
    #pragma unroll
    for (int t = 0; t < 3; ++t)
        sIdx[t][cg * 16 + row] = neigh[((size_t)t * BN_ + g) * K_ + cg];
    __syncthreads();

    // q = h_row @ Wq
    float qv[4] = {0.f, 0.f, 0.f, 0.f};
    mmrow_g(&sH[row * RS_], wb0, c0, qv);

    // ---- gather-mean + states for all 3 neighborhoods (row-local) ----
    #pragma unroll 1
    for (int t = 0; t < 3; ++t) {
        float4 s = make_float4(0.f, 0.f, 0.f, 0.f);
        int cnt = 0;
        #pragma unroll
        for (int k = 0; k < K_; ++k) {
            int idx = sIdx[t][k * 16 + row];
            if (idx != pad) {
                float4 v = hb4[(size_t)idx * 16 + cg];
                s.x += v.x; s.y += v.y; s.z += v.z; s.w += v.w;
                cnt++;
            }
        }
        float inv = 1.f / fmaxf((float)cnt, 1.f);
        *(float4*)&sM[t][row * RS_ + c0] =
            make_float4(s.x * inv, s.y * inv, s.z * inv, s.w * inv);

        float sr[4] = {0.f, 0.f, 0.f, 0.f};
        mmrow_g(&sM[t][row * RS_], wb1, c0, sr);      // mean @ nbW
        *(float4*)&sM[t][row * RS_ + c0] =
            make_float4(tanhf(sr[0]), tanhf(sr[1]), tanhf(sr[2]), tanhf(sr[3]));
    }
    __syncthreads();

    // ---- phase 1: Wk|Wv; kk,vv + scores ----
    stageW(wb0, Wk, tx);
    stageW(wb1, Wv, tx);
    __syncthreads();

    float av[3][4];
    float p[3];
    #pragma unroll 1
    for (int t = 0; t < 3; ++t) {
        float ak[4] = {0.f, 0.f, 0.f, 0.f};
        av[t][0] = av[t][1] = av[t][2] = av[t][3] = 0.f;
        mmrow_kv(&sM[t][row * RS_], wb0, wb1, c0, ak, av[t]);
        float pp = ak[0] * qv[0] + ak[1] * qv[1] + ak[2] * qv[2] + ak[3] * qv[3];
        pp += __shfl_xor(pp, 1, 64);
        pp += __shfl_xor(pp, 2, 64);
        p[t] = pp * 0.25f;                  // / sqrt(dh=16)
    }

    // softmax over t; ao -> sX row
    float mx = fmaxf(p[0], fmaxf(p[1], p[2]));
    float e0 = expf(p[0] - mx), e1 = expf(p[1] - mx), e2 = expf(p[2] - mx);
    float winv = 1.f / (e0 + e1 + e2);
    float w0 = e0 * winv, w1 = e1 * winv, w2 = e2 * winv;
    *(float4*)&sX[row * RS_ + c0] = make_float4(
        w0 * av[0][0] + w1 * av[1][0] + w2 * av[2][0],
        w0 * av[0][1] + w1 * av[1][1] + w2 * av[2][1],
        w0 * av[0][2] + w1 * av[1][2] + w2 * av[2][2],
        w0 * av[0][3] + w1 * av[1][3] + w2 * av[2][3]);
    __syncthreads();

    // ---- phase 2: Wo|gWz; x = tanh(ao@Wo); az = x@gWz ----
    stageW(wb0, Wo, tx);
    stageW(wb1, gWz, tx);
    __syncthreads();
    float xr[4] = {0.f, 0.f, 0.f, 0.f};
    mmrow_g(&sX[row * RS_], wb0, c0, xr);             // ao @ Wo
    *(float4*)&sX[row * RS_ + c0] =
        make_float4(tanhf(xr[0]), tanhf(xr[1]), tanhf(xr[2]), tanhf(xr[3]));
    float az[4] = {0.f, 0.f, 0.f, 0.f};
    mmrow_g(&sX[row * RS_], wb1, c0, az);             // x @ gWz (own row, same wave)
    __syncthreads();

    // ---- phase 3: gUz|gWr ----
    stageW(wb0, gUz, tx);
    stageW(wb1, gWr, tx);
    __syncthreads();
    mmrow_g(&sH[row * RS_], wb0, c0, az);             // += h @ gUz
    float ar[4] = {0.f, 0.f, 0.f, 0.f};
    mmrow_g(&sX[row * RS_], wb1, c0, ar);             // x @ gWr
    __syncthreads();

    // ---- phase 4: gUr|gWh ----
    stageW(wb0, gUr, tx);
    stageW(wb1, gWh, tx);
    __syncthreads();
    mmrow_g(&sH[row * RS_], wb0, c0, ar);             // += h @ gUr

    float4 bzv = *(const float4*)&gbz[c0];
    float4 brv = *(const float4*)&gbr[c0];
    float4 hv  = *(const float4*)&sH[row * RS_ + c0];
    float z[4], rr[4];
    z[0] = 1.f / (1.f + expf(-(az[0] + bzv.x)));
    z[1] = 1.f / (1.f + expf(-(az[1] + bzv.y)));
    z[2] = 1.f / (1.f + expf(-(az[2] + bzv.z)));
    z[3] = 1.f / (1.f + expf(-(az[3] + bzv.w)));
    rr[0] = 1.f / (1.f + expf(-(ar[0] + brv.x)));
    rr[1] = 1.f / (1.f + expf(-(ar[1] + brv.y)));
    rr[2] = 1.f / (1.f + expf(-(ar[2] + brv.z)));
    rr[3] = 1.f / (1.f + expf(-(ar[3] + brv.w)));
    *(float4*)&sM[0][row * RS_ + c0] =                // rh tile (sM[0] is dead)
        make_float4(rr[0] * hv.x, rr[1] * hv.y, rr[2] * hv.z, rr[3] * hv.w);

    float ah[4] = {0.f, 0.f, 0.f, 0.f};
    mmrow_g(&sX[row * RS_], wb1, c0, ah);             // x @ gWh
    __syncthreads();

    // ---- phase 5: gUh ----
    stageW(wb0, gUh, tx);
    __syncthreads();
    mmrow_g(&sM[0][row * RS_], wb0, c0, ah);          // += rh @ gUh

    float4 bhv = *(const float4*)&gbh[c0];
    float o0 = (1.f - z[0]) * hv.x + z[0] * tanhf(ah[0] + bhv.x);
    float o1 = (1.f - z[1]) * hv.y + z[1] * tanhf(ah[1] + bhv.y);
    float o2 = (1.f - z[2]) * hv.z + z[2] * tanhf(ah[2] + bhv.z);
    float o3 = (1.f - z[3]) * hv.w + z[3] * tanhf(ah[3] + bhv.w);
    *(float4*)&hout[(size_t)g * 64 + c0] = make_float4(o0, o1, o2, o3);
}

// ---------------- edge projection ------------------------------------------
__global__ __launch_bounds__(256) void k_edgeproj(
    const float* __restrict__ h, const float* __restrict__ W1,
    float* __restrict__ P)
{
    int wave = threadIdx.x >> 6;
    int lane = threadIdx.x & 63;
    int node = blockIdx.x * 4 + wave;      // < 20000

    float hval = h[(size_t)node * D_ + lane];
    const float* wp = (lane < 32) ? (W1 + lane) : (W1 + 64 * 32 + (lane - 32));
    float acc = 0.f;
    #pragma unroll 8
    for (int i = 0; i < D_; ++i)
        acc = fmaf(__shfl(hval, i, 64), wp[i * 32], acc);
    P[(size_t)node * D_ + lane] = acc;
}

// ---------------- edge decoder (light) --------------------------------------
__global__ __launch_bounds__(256) void k_decoder2(
    const float* __restrict__ P, const int* __restrict__ adj,
    const float* __restrict__ b1, const float* __restrict__ W2,
    const float* __restrict__ b2, const int* __restrict__ num_nodes,
    float* __restrict__ nw)
{
    int half = threadIdx.x >> 5;   // 0..7
    int j    = threadIdx.x & 31;
    float bias = b1[j], w2 = W2[j], b2v = b2[0];

    #pragma unroll 1
    for (int p = 0; p < 16; ++p) {
        int e = blockIdx.x * 128 + p * 8 + half;  // edge id < 320000
        int node = e >> 4;                        // b*N+n
        int b = node / N_;
        int a = adj[e];
        int pad = num_nodes[b];
        float own = P[(size_t)node * D_ + j];
        bool pd = (a == pad);
        float nbr = pd ? 0.f : P[((size_t)b * N_ + a) * D_ + 32 + j];
        float am = pd ? 0.f : 1.f;
        float t = tanhf(bias + am * own + nbr);
        float part = t * w2;
        #pragma unroll
        for (int m = 1; m < 32; m <<= 1) part += __shfl_xor(part, m, 64);
        if (j == 0) nw[e] = part + b2v;
    }
}

// ---------------- dual vars (per node scalar) + dual_demand -----------------
__global__ __launch_bounds__(256) void k_dualvars(
    const float* __restrict__ h, const float* __restrict__ W1,
    const float* __restrict__ b1, const float* __restrict__ W2,
    const float* __restrict__ b2, const float* __restrict__ demands,
    const int* __restrict__ num_nodes,
    float* __restrict__ dv, float* __restrict__ acc_out)
{
    __shared__ float sW1[D_ * 32];
    __shared__ float sW2[32];
    __shared__ float sPart[8];
    for (int i = threadIdx.x; i < D_ * 32; i += 256) sW1[i] = W1[i];
    if (threadIdx.x < 32) sW2[threadIdx.x] = W2[threadIdx.x];
    __syncthreads();

    int half = threadIdx.x >> 5;
    int j    = threadIdx.x & 31;
    int b = (blockIdx.x * 40) / N_;
    float bias = b1[j], b2v = b2[0];
    float local = 0.f;

    #pragma unroll 1
    for (int p = 0; p < 5; ++p) {
        int node = blockIdx.x * 40 + p * 8 + half;    // < 20000
        const float* hp = h + (size_t)node * D_;
        float h0 = hp[j], h1 = hp[j + 32];
        float acc = bias;
        #pragma unroll 8
        for (int i = 0; i < 32; ++i) {
            acc = fmaf(__shfl(h0, i, 32), sW1[i * 32 + j],        acc);
            acc = fmaf(__shfl(h1, i, 32), sW1[(i + 32) * 32 + j], acc);
        }
        float t = tanhf(acc);
        float part = t * sW2[j];
        #pragma unroll
        for (int m = 1; m < 32; m <<= 1) part += __shfl_xor(part, m, 64);
        if (j == 0) {
            float v = part + b2v;
            dv[node] = v;
            local += v * demands[node];
        }
    }
    if (j == 0) sPart[half] = local;
    __syncthreads();
    if (threadIdx.x == 0) {
        float s = 0.f;
        #pragma unroll
        for (int i = 0; i < 8; ++i) s += sPart[i];
        atomicAdd(&acc_out[(b * 3 + 2) * 16], s);
    }
}

// ---------------- dest softmax over permuted groups -------------------------
__global__ void k_dest(
    const float* __restrict__ nw, const int* __restrict__ in_idx,
    const int* __restrict__ inv_adj, const int* __restrict__ num_nodes,
    float* __restrict__ dest)
{
    int t = blockIdx.x * 256 + threadIdx.x;
    if (t >= BN_) return;
    int b = t / N_;
    int pad = num_nodes[b];
    float vals[K_]; float mx = -INFINITY;
    #pragma unroll
    for (int k = 0; k < K_; ++k) {
        int jj = in_idx[(size_t)t * K_ + k];
        float g = nw[(size_t)b * NK_ + jj];
        float im = (inv_adj[(size_t)t * K_ + k] == pad) ? 1.f : 0.f;
        float v = g - BIG_ * im;
        vals[k] = v; mx = fmaxf(mx, v);
    }
    float s = 0.f;
    #pragma unroll
    for (int k = 0; k < K_; ++k) { vals[k] = expf(vals[k] - mx); s += vals[k]; }
    float invs = 1.f / s;
    #pragma unroll
    for (int k = 0; k < K_; ++k) dest[(size_t)t * K_ + k] = vals[k] * invs;
}

// ---------------- normalized_weights + flow0 --------------------------------
__global__ void k_normw(
    const float* __restrict__ nw, const float* __restrict__ dest,
    const int* __restrict__ rev, const int* __restrict__ adj,
    const int* __restrict__ num_nodes, const float* __restrict__ demands,
    float* __restrict__ normw, float* __restrict__ flow0)
{
    int t = blockIdx.x * 256 + threadIdx.x;
    if (t >= BN_) return;
    int b = t / N_;
    int pad = num_nodes[b];
    float vals[K_]; float mx = -INFINITY;
    #pragma unroll
    for (int k = 0; k < K_; ++k) {
        size_t e = (size_t)t * K_ + k;
        float v = nw[e] * dest[(size_t)b * NK_ + rev[e]];
        float m = (adj[e] == pad) ? 1.f : 0.f;
        v -= BIG_ * m;
        vals[k] = v; mx = fmaxf(mx, v);
    }
    float s = 0.f;
    #pragma unroll
    for (int k = 0; k < K_; ++k) { vals[k] = expf(vals[k] - mx); s += vals[k]; }
    float invs = 1.f / s;
    float supply = fmaxf(-demands[t], 0.f);
    #pragma unroll
    for (int k = 0; k < K_; ++k) {
        float w = vals[k] * invs;
        normw[(size_t)t * K_ + k] = w;
        flow0[(size_t)t * K_ + k] = w * supply;
    }
}

// ---------------- one MCF flow step -----------------------------------------
__global__ void k_flow(
    const float* __restrict__ cur, const float* __restrict__ normw,
    const int* __restrict__ in_idx, const int* __restrict__ inv_adj,
    const int* __restrict__ num_nodes, const float* __restrict__ demands,
    float* __restrict__ nxt)
{
    int t = blockIdx.x * 256 + threadIdx.x;
    if (t >= BN_) return;
    int b = t / N_;
    int pad = num_nodes[b];
    float inflow = 0.f;
    #pragma unroll
    for (int k = 0; k < K_; ++k) {
        size_t e = (size_t)t * K_ + k;
        if (inv_adj[e] != pad) inflow += cur[(size_t)b * NK_ + in_idx[e]];
    }
    float tot = inflow + fmaxf(-demands[t], 0.f);
    #pragma unroll
    for (int k = 0; k < K_; ++k)
        nxt[(size_t)t * K_ + k] = normw[(size_t)t * K_ + k] * tot;
}

// ---------------- dual iterations + both cost reductions (dd fused) ---------
__global__ __launch_bounds__(256) void k_dualred(
    const float* __restrict__ el, const float* __restrict__ dv,
    const int* __restrict__ adj, const int* __restrict__ num_nodes,
    const float* __restrict__ flow, float* __restrict__ acc_out)
{
    int b = blockIdx.y;
    int ein = blockIdx.x * 256 + threadIdx.x;
    float c0 = 0.f, c1 = 0.f;
    if (ein < NK_) {
        size_t e = (size_t)b * NK_ + ein;
        int pad = num_nodes[b];
        int node = b * N_ + (ein >> 4);
        int a = adj[e];
        float am = (a == pad) ? 0.f : 1.f;
        float dtr = (a == pad) ? 0.f : dv[(size_t)b * N_ + a];
        float d = dtr - am * dv[node];
        float l = el[e];
        float f = 0.f, ac = 0.f;
        #pragma unroll
        for (int it = 0; it < 10; ++it) {
            float g = 2.f * l * f + d;
            ac = 0.9f * ac + 0.01f * g;
            f = fmaxf(f - ac, 0.f) * am;
        }
        float fl = flow[e];
        c0 = l * fl * fl;          // flow_cost term
        c1 = l * f * f + d * f;    // dual flow term
    }
    #pragma unroll
    for (int m = 1; m < 64; m <<= 1) { c0 += __shfl_xor(c0, m, 64); c1 += __shfl_xor(c1, m, 64); }
    __shared__ float s0[4], s1[4];
    int wave = threadIdx.x >> 6, lane = threadIdx.x & 63;
    if (lane == 0) { s0[wave] = c0; s1[wave] = c1; }
    __syncthreads();
    if (threadIdx.x == 0) {
        atomicAdd(&acc_out[(b * 3 + 0) * 16], s0[0] + s0[1] + s0[2] + s0[3]);
        atomicAdd(&acc_out[(b * 3 + 1) * 16], s1[0] + s1[1] + s1[2] + s1[3]);
    }
}

// ---------------- finalize --------------------------------------------------
__global__ void k_final(const float* __restrict__ acc, float* __restrict__ out) {
    int b = threadIdx.x;
    if (b < B_)
        out[b] = acc[(b * 3 + 0) * 16] - acc[(b * 3 + 1) * 16] + acc[(b * 3 + 2) * 16];
}

extern "C" void kernel_launch(void* const* d_in, const int* in_sizes, int n_in,
                              void* d_out, int out_size, void* d_ws, size_t ws_size,
                              hipStream_t stream)
{
    const float* demands = (const float*)d_in[0];
    const float* feat    = (const float*)d_in[1];
    const float* el      = (const float*)d_in[2];
    const float* embed   = (const float*)d_in[3];
    const float* encW    = (const float*)d_in[4];
    const float* encb    = (const float*)d_in[5];
    const float* nbW     = (const float*)d_in[6];
    const float* Wq      = (const float*)d_in[7];
    const float* Wk      = (const float*)d_in[8];
    const float* Wv      = (const float*)d_in[9];
    const float* Wo      = (const float*)d_in[10];
    const float* gWz     = (const float*)d_in[11];
    const float* gUz     = (const float*)d_in[12];
    const float* gbz     = (const float*)d_in[13];
    const float* gWr     = (const float*)d_in[14];
    const float* gUr     = (const float*)d_in[15];
    const float* gbr     = (const float*)d_in[16];
    const float* gWh     = (const float*)d_in[17];
    const float* gUh     = (const float*)d_in[18];
    const float* gbh     = (const float*)d_in[19];
    const float* decW1   = (const float*)d_in[20];
    const float* decb1   = (const float*)d_in[21];
    const float* decW2   = (const float*)d_in[22];
    const float* decb2   = (const float*)d_in[23];
    const float* dualW1  = (const float*)d_in[24];
    const float* dualb1  = (const float*)d_in[25];
    const float* dualW2  = (const float*)d_in[26];
    const float* dualb2  = (const float*)d_in[27];
    const int* adj       = (const int*)d_in[28];
    const int* invadj    = (const int*)d_in[29];
    const int* neigh     = (const int*)d_in[30];
    const int* inidx     = (const int*)d_in[31];
    const int* revidx    = (const int*)d_in[32];
    const int* numn      = (const int*)d_in[33];

    // workspace (floats)
    float* ws    = (float*)d_ws;
    float* h0    = ws;                   // 1,280,000
    float* h1    = ws + 1280000;         // 1,280,000 (ping-pong; P after layers)
    float* fb    = ws + 2560000;         // flow region
    float* nw    = fb;                   // 320,000
    float* dest  = fb + 320000;          // 320,000
    float* normw = fb + 640000;          // 320,000
    float* flowA = fb + 960000;          // 320,000
    float* flowB = fb + 1280000;         // 320,000
    float* dv    = fb + 1600000;         // 20,000
    float* P     = h1;                   // reuse (h1 dead after layer 1)
    float* acc   = ws + 4200000;         // 192

    k_zero<<<1, 256, 0, stream>>>(acc);
    k_encode<<<BN_ / 4, 256, 0, stream>>>(embed, feat, encW, encb, h0);

    // layer 0: h0 -> h1 ; layer 1: h1 -> h0  (gathers must read pre-layer h)
    k_layer<<<BN_ / 16, 256, 0, stream>>>(h0, h1, neigh, numn, nbW, Wq, Wk, Wv, Wo,
                                          gWz, gUz, gbz, gWr, gUr, gbr, gWh, gUh, gbh);
    k_layer<<<BN_ / 16, 256, 0, stream>>>(h1, h0, neigh, numn, nbW, Wq, Wk, Wv, Wo,
                                          gWz, gUz, gbz, gWr, gUr, gbr, gWh, gUh, gbh);
    float* h = h0;

    k_edgeproj<<<BN_ / 4, 256, 0, stream>>>(h, decW1, P);
    k_decoder2<<<(B_ * NK_) / 128, 256, 0, stream>>>(P, adj, decb1, decW2, decb2, numn, nw);
    k_dualvars<<<BN_ / 40, 256, 0, stream>>>(h, dualW1, dualb1, dualW2, dualb2, demands, numn, dv, acc);
    k_dest<<<(BN_ + 255) / 256, 256, 0, stream>>>(nw, inidx, invadj, numn, dest);
    k_normw<<<(BN_ + 255) / 256, 256, 0, stream>>>(nw, dest, revidx, adj, numn, demands, normw, flowA);

    float* cur = flowA; float* nxt = flowB;
    for (int it = 0; it < 10; ++it) {
        k_flow<<<(BN_ + 255) / 256, 256, 0, stream>>>(cur, normw, inidx, invadj, numn, demands, nxt);
        float* tmp = cur; cur = nxt; nxt = tmp;
    }

    dim3 gred((NK_ + 255) / 256, B_);
    k_dualred<<<gred, 256, 0, stream>>>(el, dv, adj, numn, cur, acc);
    k_final<<<1, 64, 0, stream>>>(acc, (float*)d_out);
}